// Round 8
// baseline (2770.459 us; speedup 1.0000x reference)
//
#include <hip/hip_runtime.h>
#include <hip/hip_cooperative_groups.h>
#include <math.h>

namespace cg = cooperative_groups;

#define B_SZ   2
#define L_SEQ  4096
#define DIMC   128
#define DI     256      // D_INNER
#define DST    16       // D_STATE
#define DTR    8        // DT_RANK
#define NXP    40       // DTR + 2*DST
#define NXPP   48       // padded to MFMA tile
#define NLAYER 8
#define NCH    256      // chunks per batch
#define CS     16       // rows per chunk
#define LOG2E  1.4426950408889634f
#define LN2    0.6931471805599453f
#define PSA    264      // u16 LDS row stride for MFMA A tiles
#define NBLK   512
#define NTHR   256

#define N_INW  (NLAYER * 512 * 128)
#define N_XPW  (NLAYER * NXPP * DI)
#define N_OW   (NLAYER * DIMC * DI)
#define N_AF   (NLAYER * DI * DST)

typedef __attribute__((ext_vector_type(8))) unsigned short u16x8;
typedef __attribute__((ext_vector_type(4))) float f32x4;

__device__ __forceinline__ float fexp2(float x){ float r; asm("v_exp_f32 %0, %1" : "=v"(r) : "v"(x)); return r; }
__device__ __forceinline__ float flog2(float x){ float r; asm("v_log_f32 %0, %1" : "=v"(r) : "v"(x)); return r; }
__device__ __forceinline__ float frcp (float x){ float r; asm("v_rcp_f32 %0, %1" : "=v"(r) : "v"(x)); return r; }

__device__ __forceinline__ float silu_f(float x) {
    return x * frcp(1.f + fexp2(-x * LOG2E));
}
__device__ __forceinline__ float softplus_f(float x) {
    float t = fexp2(-fabsf(x) * LOG2E);
    return fmaxf(x, 0.f) + flog2(1.f + t) * LN2;
}
__device__ __forceinline__ void splitf(float x, unsigned short& h, unsigned short& l) {
    unsigned bx = __builtin_bit_cast(unsigned, x);
    h = (unsigned short)(bx >> 16);
    float fh = __builtin_bit_cast(float, bx & 0xffff0000u);
    float r = x - fh;
    l = (unsigned short)(__builtin_bit_cast(unsigned, r) >> 16);
}
__device__ __forceinline__ float bf2f(unsigned short u) {
    return __builtin_bit_cast(float, (unsigned)u << 16);
}

struct MParams {
    const float *x, *in_w, *conv_w, *conv_b, *xp_w, *dt_w, *dt_b, *A_log, *D_skip, *out_w, *rms_w;
    float *out;
    float *xz, *xdbl, *paB, *hB, *AfT;
    unsigned short *hh0, *hl0, *hh1, *hl1, *iwh, *iwl, *xpwh, *xpwl, *owh, *owl;
};

__global__ __launch_bounds__(NTHR, 2) void mega(MParams p) {
    __shared__ __align__(16) char smem[33280];
    const int bid = blockIdx.x;
    const int t   = threadIdx.x;
    cg::grid_group grid = cg::this_grid();

    // ===== P0: weight split + Af table =====
    for (int i = bid * NTHR + t; i < N_INW; i += NBLK * NTHR) {
        { unsigned short h, l; splitf(p.in_w[i], h, l); p.iwh[i] = h; p.iwl[i] = l; }
        if (i < N_XPW) {
            int ly = i / (NXPP * DI), rem = i % (NXPP * DI);
            int c = rem / DI, k = rem % DI;
            unsigned short h = 0, l = 0;
            if (c < NXP) splitf(p.xp_w[((size_t)ly * NXP + c) * DI + k], h, l);
            p.xpwh[i] = h; p.xpwl[i] = l;
        }
        if (i < N_OW) { unsigned short h, l; splitf(p.out_w[i], h, l); p.owh[i] = h; p.owl[i] = l; }
        if (i < N_AF) p.AfT[i] = -expf(p.A_log[i]) * LOG2E;
    }

    // ===== P0b: transpose x (B,C,L) -> split bf16 (B,L,C) =====
    {
        float (*tl)[33] = (float (*)[33])smem;
        const int tx = t & 31, ty = t >> 5;   // 32 x 8
        for (int tile = bid; tile < B_SZ * (DIMC / 32) * (L_SEQ / 32); tile += NBLK) {
            const int b   = tile / ((DIMC / 32) * (L_SEQ / 32));
            const int rem = tile % ((DIMC / 32) * (L_SEQ / 32));
            const int c0  = (rem / (L_SEQ / 32)) * 32;
            const int l0  = (rem % (L_SEQ / 32)) * 32;
            __syncthreads();
            #pragma unroll
            for (int r = 0; r < 4; ++r) {
                int c = c0 + ty + r * 8;
                tl[ty + r * 8][tx] = p.x[((size_t)b * DIMC + c) * L_SEQ + l0 + tx];
            }
            __syncthreads();
            #pragma unroll
            for (int r = 0; r < 4; ++r) {
                int l = l0 + ty + r * 8;
                float v = tl[tx][ty + r * 8];
                size_t o = ((size_t)b * L_SEQ + l) * DIMC + c0 + tx;
                unsigned short h16, l16; splitf(v, h16, l16);
                p.hh0[o] = h16; p.hl0[o] = l16;
            }
        }
    }

    grid.sync();

    unsigned short *hhin = p.hh0, *hlin = p.hl0, *hhout = p.hh1, *hlout = p.hl1;
    const int w  = t >> 6, l = t & 63;
    const int lr = l & 15, lq = l >> 4;
    const int d  = t;
    const f32x4 z4 = {0.f, 0.f, 0.f, 0.f};

    for (int layer = 0; layer < NLAYER; ++layer) {
        const float* cw  = p.conv_w + (size_t)layer * DI * 4;
        const float* cb  = p.conv_b + (size_t)layer * DI;
        const float* dtw = p.dt_w   + (size_t)layer * DI * DTR;
        const float* dtb = p.dt_b   + (size_t)layer * DI;
        const float* af  = p.AfT    + (size_t)layer * DI * DST;
        const float* ds  = p.D_skip + (size_t)layer * DI;
        const unsigned short* liwh = p.iwh  + (size_t)layer * 512 * 128;
        const unsigned short* liwl = p.iwl  + (size_t)layer * 512 * 128;
        const unsigned short* lxph = p.xpwh + (size_t)layer * NXPP * DI;
        const unsigned short* lxpl = p.xpwl + (size_t)layer * NXPP * DI;
        const unsigned short* lowh = p.owh  + (size_t)layer * DIMC * DI;
        const unsigned short* lowl = p.owl  + (size_t)layer * DIMC * DI;

        // ===== phase 1: in_proj GEMM (64x128 tile, 128x4 = 512 tiles) =====
        {
            unsigned short* LAh = (unsigned short*)smem;        // 64*40
            unsigned short* LAl = LAh + 64 * 40;
            unsigned short* LBh = LAl + 64 * 40;                // 128*40
            unsigned short* LBl = LBh + 128 * 40;
            const int bm = (bid >> 2) * 64, bn = (bid & 3) * 128;
            const int wr = w >> 1, wc = w & 1;
            f32x4 acc[2][4];
            #pragma unroll
            for (int m = 0; m < 2; ++m)
                #pragma unroll
                for (int n = 0; n < 4; ++n) acc[m][n] = z4;
            for (int k0 = 0; k0 < 128; k0 += 32) {
                if (k0) __syncthreads();
                {
                    int r = t >> 2, g = t & 3;
                    size_t go = (size_t)(bm + r) * 128 + k0 + g * 8;
                    *(u16x8*)&LAh[r * 40 + g * 8] = *(const u16x8*)&hhin[go];
                    *(u16x8*)&LAl[r * 40 + g * 8] = *(const u16x8*)&hlin[go];
                }
                #pragma unroll
                for (int s = 0; s < 2; ++s) {
                    int task = t + s * 256;
                    int r = task >> 2, g = task & 3;
                    size_t go = (size_t)(bn + r) * 128 + k0 + g * 8;
                    *(u16x8*)&LBh[r * 40 + g * 8] = *(const u16x8*)&liwh[go];
                    *(u16x8*)&LBl[r * 40 + g * 8] = *(const u16x8*)&liwl[go];
                }
                __syncthreads();
                u16x8 ah[2], al[2], bh[4], bl[4];
                #pragma unroll
                for (int m = 0; m < 2; ++m) {
                    int rr = wr * 32 + m * 16 + lr;
                    ah[m] = *(u16x8*)&LAh[rr * 40 + lq * 8];
                    al[m] = *(u16x8*)&LAl[rr * 40 + lq * 8];
                }
                #pragma unroll
                for (int n = 0; n < 4; ++n) {
                    int rr = wc * 64 + n * 16 + lr;
                    bh[n] = *(u16x8*)&LBh[rr * 40 + lq * 8];
                    bl[n] = *(u16x8*)&LBl[rr * 40 + lq * 8];
                }
                #pragma unroll
                for (int m = 0; m < 2; ++m)
                    #pragma unroll
                    for (int n = 0; n < 4; ++n) {
                        asm("v_mfma_f32_16x16x32_bf16 %0, %1, %2, %0" : "+v"(acc[m][n]) : "v"(ah[m]), "v"(bh[n]));
                        asm("v_mfma_f32_16x16x32_bf16 %0, %1, %2, %0" : "+v"(acc[m][n]) : "v"(ah[m]), "v"(bl[n]));
                        asm("v_mfma_f32_16x16x32_bf16 %0, %1, %2, %0" : "+v"(acc[m][n]) : "v"(al[m]), "v"(bh[n]));
                    }
            }
            #pragma unroll
            for (int m = 0; m < 2; ++m)
                #pragma unroll
                for (int n = 0; n < 4; ++n) {
                    int col = bn + wc * 64 + n * 16 + lr;
                    #pragma unroll
                    for (int r = 0; r < 4; ++r) {
                        int row = bm + wr * 32 + m * 16 + lq * 4 + r;
                        p.xz[(size_t)row * 512 + col] = acc[m][n][r];
                    }
                }
        }
        grid.sync();

        // ===== phase 2: conv+silu -> x_proj MFMA -> dt -> scanA =====
        {
            unsigned short (*aS)[CS][PSA] = (unsigned short (*)[CS][PSA])smem;   // [2][16][264] = 16896 B
            float (*PP)[CS][49] = (float (*)[CS][49])(smem + 16896);             // [4][16][49]  = 12544 B
            float (*xdS)[41]    = (float (*)[41])(smem + 16896 + 12544);         // [16][41]     =  2624 B
            const int ch = bid & (NCH - 1);
            const size_t r0 = (size_t)(bid >> 8) * L_SEQ + ch * CS;

            {   // conv + silu, split into LDS
                const float w0 = cw[d * 4 + 0], w1 = cw[d * 4 + 1];
                const float w2 = cw[d * 4 + 2], w3 = cw[d * 4 + 3];
                const float bz = cb[d];
                float p0 = 0.f, p1 = 0.f, p2 = 0.f;
                if (ch > 0) {
                    p0 = p.xz[(r0 - 3) * 512 + d];
                    p1 = p.xz[(r0 - 2) * 512 + d];
                    p2 = p.xz[(r0 - 1) * 512 + d];
                }
                #pragma unroll 4
                for (int i = 0; i < CS; ++i) {
                    float cur = p.xz[(r0 + i) * 512 + d];
                    float v = silu_f(fmaf(w3, cur, fmaf(w2, p2, fmaf(w1, p1, fmaf(w0, p0, bz)))));
                    unsigned short h16, l16; splitf(v, h16, l16);
                    aS[0][i][d] = h16; aS[1][i][d] = l16;
                    p0 = p1; p1 = p2; p2 = cur;
                }
            }
            __syncthreads();

            {   // x_proj MFMA (M=16, N=48), waves split K
                f32x4 acc[3];
                #pragma unroll
                for (int n = 0; n < 3; ++n) acc[n] = z4;
                #pragma unroll
                for (int ks = 0; ks < 2; ++ks) {
                    const int kk = w * 64 + ks * 32 + lq * 8;
                    u16x8 ah, al, bh[3], bl[3];
                    ah = *(const u16x8*)&aS[0][lr][kk];
                    al = *(const u16x8*)&aS[1][lr][kk];
                    #pragma unroll
                    for (int n = 0; n < 3; ++n) {
                        const int c = n * 16 + lr;
                        bh[n] = *(const u16x8*)&lxph[c * DI + kk];
                        bl[n] = *(const u16x8*)&lxpl[c * DI + kk];
                    }
                    #pragma unroll
                    for (int n = 0; n < 3; ++n) {
                        asm("v_mfma_f32_16x16x32_bf16 %0, %1, %2, %0" : "+v"(acc[n]) : "v"(ah), "v"(bh[n]));
                        asm("v_mfma_f32_16x16x32_bf16 %0, %1, %2, %0" : "+v"(acc[n]) : "v"(ah), "v"(bl[n]));
                        asm("v_mfma_f32_16x16x32_bf16 %0, %1, %2, %0" : "+v"(acc[n]) : "v"(al), "v"(bh[n]));
                    }
                }
                #pragma unroll
                for (int n = 0; n < 3; ++n)
                    #pragma unroll
                    for (int r = 0; r < 4; ++r)
                        PP[w][lq * 4 + r][n * 16 + lr] = acc[n][r];
            }
            __syncthreads();
            {   // reduce 4 partials -> xdS + global xdbl
                const int i = t >> 4;
                const int c0 = t & 15;
                for (int c = c0; c < NXP; c += 16) {
                    float s = PP[0][i][c] + PP[1][i][c] + PP[2][i][c] + PP[3][i][c];
                    xdS[i][c] = s;
                    p.xdbl[(r0 + i) * NXP + c] = s;
                }
            }
            __syncthreads();

            {   // dt + softplus + scanA (zero init)
                float wt[DTR];
                #pragma unroll
                for (int r = 0; r < DTR; ++r) wt[r] = dtw[d * DTR + r];
                const float bt = dtb[d];
                float Af[DST], h[DST], pa[DST];
                #pragma unroll
                for (int n = 0; n < DST; ++n) {
                    Af[n] = af[d * DST + n];
                    h[n] = 0.f; pa[n] = 1.f;
                }
                #pragma unroll 4
                for (int i = 0; i < CS; ++i) {
                    float s = bt;
                    #pragma unroll
                    for (int r = 0; r < DTR; ++r) s = fmaf(xdS[i][r], wt[r], s);
                    const float dl = softplus_f(s);
                    const float u = bf2f(aS[0][i][d]) + bf2f(aS[1][i][d]);
                    const float du = dl * u;
                    #pragma unroll
                    for (int n = 0; n < DST; ++n) {
                        const float dA = fexp2(dl * Af[n]);
                        pa[n] *= dA;
                        h[n] = fmaf(dA, h[n], du * xdS[i][DTR + n]);
                    }
                }
                const size_t o = ((size_t)bid * DI + d) * DST;
                #pragma unroll
                for (int n = 0; n < DST; ++n) { p.paB[o + n] = pa[n]; p.hB[o + n] = h[n]; }
            }
        }
        grid.sync();

        // ===== phase 3: combine chunk states (blocks 0..31) =====
        if (bid < 32) {
            const int tt = bid * NTHR + t;          // 0..8191
            const int b  = tt / (DI * DST);
            const int dn = tt % (DI * DST);
            float run = 0.f;
            for (int ch0 = 0; ch0 < NCH; ch0 += 8) {
                float pav[8], hv[8];
                #pragma unroll
                for (int j = 0; j < 8; ++j) {
                    size_t o = ((size_t)(b * NCH + ch0 + j)) * DI * DST + dn;
                    pav[j] = p.paB[o]; hv[j] = p.hB[o];
                }
                #pragma unroll
                for (int j = 0; j < 8; ++j) {
                    size_t o = ((size_t)(b * NCH + ch0 + j)) * DI * DST + dn;
                    p.paB[o] = run;
                    run = fmaf(pav[j], run, hv[j]);
                }
            }
        }
        grid.sync();

        // ===== phase 4: conv recompute -> scanC + gate -> out_proj MFMA =====
        {
            unsigned short (*yS)[CS][PSA] = (unsigned short (*)[CS][PSA])smem;   // [2][16][264] = 16896 B
            float (*xdS)[41] = (float (*)[41])(smem + 16896);                    // [16][41]     =  2624 B
            const int ch = bid & (NCH - 1);
            const size_t r0 = (size_t)(bid >> 8) * L_SEQ + ch * CS;

            {
                const float* src = p.xdbl + r0 * NXP;
                for (int idx = t; idx < CS * NXP; idx += NTHR)
                    xdS[idx / NXP][idx % NXP] = src[idx];
            }
            float wt[DTR];
            #pragma unroll
            for (int r = 0; r < DTR; ++r) wt[r] = dtw[d * DTR + r];
            const float bt = dtb[d];
            const float Dd = ds[d];
            const float w0 = cw[d * 4 + 0], w1 = cw[d * 4 + 1];
            const float w2 = cw[d * 4 + 2], w3 = cw[d * 4 + 3];
            const float bz = cb[d];
            float Af[DST], h[DST];
            const size_t o = ((size_t)bid * DI + d) * DST;
            #pragma unroll
            for (int n = 0; n < DST; ++n) {
                Af[n] = af[d * DST + n];
                h[n] = p.paB[o + n];
            }
            float p0 = 0.f, p1 = 0.f, p2 = 0.f;
            if (ch > 0) {
                p0 = p.xz[(r0 - 3) * 512 + d];
                p1 = p.xz[(r0 - 2) * 512 + d];
                p2 = p.xz[(r0 - 1) * 512 + d];
            }
            __syncthreads();

            #pragma unroll 4
            for (int i = 0; i < CS; ++i) {
                const float cur = p.xz[(r0 + i) * 512 + d];
                const float zv  = p.xz[(r0 + i) * 512 + DI + d];
                const float u = silu_f(fmaf(w3, cur, fmaf(w2, p2, fmaf(w1, p1, fmaf(w0, p0, bz)))));
                p0 = p1; p1 = p2; p2 = cur;
                float s = bt;
                #pragma unroll
                for (int r = 0; r < DTR; ++r) s = fmaf(xdS[i][r], wt[r], s);
                const float dl = softplus_f(s);
                const float du = dl * u;
                float acc = 0.f;
                #pragma unroll
                for (int n = 0; n < DST; ++n) {
                    const float dA = fexp2(dl * Af[n]);
                    h[n] = fmaf(dA, h[n], du * xdS[i][DTR + n]);
                    acc = fmaf(h[n], xdS[i][DTR + DST + n], acc);
                }
                const float y = (acc + u * Dd) * silu_f(zv);
                unsigned short h16, l16; splitf(y, h16, l16);
                yS[0][i][d] = h16; yS[1][i][d] = l16;
            }
            __syncthreads();

            {   // out_proj MFMA: M=16, wave w owns cols w*32.., K=256
                f32x4 acc[2];
                #pragma unroll
                for (int n = 0; n < 2; ++n) acc[n] = z4;
                #pragma unroll
                for (int ks = 0; ks < 8; ++ks) {
                    const int kk = ks * 32 + lq * 8;
                    u16x8 ah, al, bh[2], bl[2];
                    ah = *(const u16x8*)&yS[0][lr][kk];
                    al = *(const u16x8*)&yS[1][lr][kk];
                    #pragma unroll
                    for (int n = 0; n < 2; ++n) {
                        const int c = w * 32 + n * 16 + lr;
                        bh[n] = *(const u16x8*)&lowh[c * DI + kk];
                        bl[n] = *(const u16x8*)&lowl[c * DI + kk];
                    }
                    #pragma unroll
                    for (int n = 0; n < 2; ++n) {
                        asm("v_mfma_f32_16x16x32_bf16 %0, %1, %2, %0" : "+v"(acc[n]) : "v"(ah), "v"(bh[n]));
                        asm("v_mfma_f32_16x16x32_bf16 %0, %1, %2, %0" : "+v"(acc[n]) : "v"(ah), "v"(bl[n]));
                        asm("v_mfma_f32_16x16x32_bf16 %0, %1, %2, %0" : "+v"(acc[n]) : "v"(al), "v"(bh[n]));
                    }
                }
                #pragma unroll
                for (int n = 0; n < 2; ++n) {
                    const int col = w * 32 + n * 16 + lr;
                    #pragma unroll
                    for (int r = 0; r < 4; ++r) {
                        const size_t row = r0 + lq * 4 + r;
                        unsigned short h16, l16; splitf(acc[n][r], h16, l16);
                        hhout[row * DIMC + col] = h16;
                        hlout[row * DIMC + col] = l16;
                    }
                }
            }
        }
        grid.sync();

        unsigned short* ts;
        ts = hhin; hhin = hhout; hhout = ts;
        ts = hlin; hlin = hlout; hlout = ts;
    }

    // ===== RMSNorm + transpose out (blocks 0..127) =====
    if (bid < B_SZ * (L_SEQ / 64)) {
        float (*tile)[129] = (float (*)[129])smem;                 // 64*129*4 = 33024 B
        float* rinv = (float*)(smem + 64 * 129 * 4);               // 256 B
        const int b  = bid / (L_SEQ / 64);
        const int l0 = (bid % (L_SEQ / 64)) * 64;
        for (int k = 0; k < 32; ++k) {
            int idx = k * 256 + t;
            int ll = idx >> 7, cc = idx & 127;
            size_t o = ((size_t)b * L_SEQ + l0 + ll) * DIMC + cc;
            tile[ll][cc] = bf2f(hhin[o]) + bf2f(hlin[o]);
        }
        __syncthreads();
        if (t < 64) {
            float s = 0.f;
            for (int cc = 0; cc < DIMC; ++cc) { float v = tile[t][cc]; s += v * v; }
            rinv[t] = rsqrtf(s / DIMC + 1e-6f);
        }
        __syncthreads();
        for (int k = 0; k < 32; ++k) {
            int odx = k * 256 + t;
            int cc = odx >> 6, li = odx & 63;
            p.out[((size_t)b * DIMC + cc) * L_SEQ + l0 + li] = tile[li][cc] * rinv[li] * p.rms_w[cc];
        }
    }
}

extern "C" void kernel_launch(void* const* d_in, const int* in_sizes, int n_in,
                              void* d_out, int out_size, void* d_ws, size_t ws_size,
                              hipStream_t stream) {
    const int M = B_SZ * L_SEQ;   // 8192
    char* pws = (char*)d_ws;
    auto alloc = [&](size_t bytes) -> void* {
        void* r = (void*)pws; pws += (bytes + 255) & ~(size_t)255; return r;
    };
    MParams prm;
    prm.x      = (const float*)d_in[0];
    prm.in_w   = (const float*)d_in[1];
    prm.conv_w = (const float*)d_in[2];
    prm.conv_b = (const float*)d_in[3];
    prm.xp_w   = (const float*)d_in[4];
    prm.dt_w   = (const float*)d_in[5];
    prm.dt_b   = (const float*)d_in[6];
    prm.A_log  = (const float*)d_in[7];
    prm.D_skip = (const float*)d_in[8];
    prm.out_w  = (const float*)d_in[9];
    prm.rms_w  = (const float*)d_in[10];
    prm.out    = (float*)d_out;

    prm.xz   = (float*)alloc((size_t)M * 512 * 4);
    prm.xdbl = (float*)alloc((size_t)M * NXP * 4);
    prm.paB  = (float*)alloc((size_t)B_SZ * NCH * DI * DST * 4);
    prm.hB   = (float*)alloc((size_t)B_SZ * NCH * DI * DST * 4);
    prm.AfT  = (float*)alloc((size_t)N_AF * 4);
    prm.hh0  = (unsigned short*)alloc((size_t)M * DIMC * 2);
    prm.hl0  = (unsigned short*)alloc((size_t)M * DIMC * 2);
    prm.hh1  = (unsigned short*)alloc((size_t)M * DIMC * 2);
    prm.hl1  = (unsigned short*)alloc((size_t)M * DIMC * 2);
    prm.iwh  = (unsigned short*)alloc((size_t)N_INW * 2);
    prm.iwl  = (unsigned short*)alloc((size_t)N_INW * 2);
    prm.xpwh = (unsigned short*)alloc((size_t)N_XPW * 2);
    prm.xpwl = (unsigned short*)alloc((size_t)N_XPW * 2);
    prm.owh  = (unsigned short*)alloc((size_t)N_OW * 2);
    prm.owl  = (unsigned short*)alloc((size_t)N_OW * 2);

    void* args[] = { &prm };
    hipLaunchCooperativeKernel((const void*)mega, dim3(NBLK), dim3(NTHR), args, 0, stream);
}

// Round 10
// 552.894 us; speedup vs baseline: 5.0108x; 5.0108x over previous
//
#include <hip/hip_runtime.h>
#include <math.h>

#define B_SZ   2
#define L_SEQ  4096
#define DIMC   128
#define DI     256      // D_INNER
#define DST    16       // D_STATE
#define DTR    8        // DT_RANK
#define NXP    40       // DTR + 2*DST
#define NXPP   48       // padded to MFMA tile
#define NLAYER 8
#define NCH    256      // chunks per batch
#define CS     16       // rows per chunk
#define LOG2E  1.4426950408889634f
#define LN2    0.6931471805599453f
#define PSA    264      // u16 LDS row stride for MFMA A tiles

#define N_INW  (NLAYER * 512 * 128)
#define N_XPW  (NLAYER * NXPP * DI)
#define N_OW   (NLAYER * DIMC * DI)
#define N_AF   (NLAYER * DI * DST)

typedef __attribute__((ext_vector_type(8))) unsigned short u16x8;
typedef __attribute__((ext_vector_type(4))) float f32x4;

__device__ __forceinline__ float fexp2(float x){ float r; asm("v_exp_f32 %0, %1" : "=v"(r) : "v"(x)); return r; }
__device__ __forceinline__ float flog2(float x){ float r; asm("v_log_f32 %0, %1" : "=v"(r) : "v"(x)); return r; }
__device__ __forceinline__ float frcp (float x){ float r; asm("v_rcp_f32 %0, %1" : "=v"(r) : "v"(x)); return r; }

__device__ __forceinline__ float silu_f(float x) {
    return x * frcp(1.f + fexp2(-x * LOG2E));
}
__device__ __forceinline__ float softplus_f(float x) {
    float t = fexp2(-fabsf(x) * LOG2E);
    return fmaxf(x, 0.f) + flog2(1.f + t) * LN2;
}
__device__ __forceinline__ void splitf(float x, unsigned short& h, unsigned short& l) {
    unsigned bx = __builtin_bit_cast(unsigned, x);
    h = (unsigned short)(bx >> 16);
    float fh = __builtin_bit_cast(float, bx & 0xffff0000u);
    float r = x - fh;
    l = (unsigned short)(__builtin_bit_cast(unsigned, r) >> 16);
}
__device__ __forceinline__ float bf2f(unsigned short u) {
    return __builtin_bit_cast(float, (unsigned)u << 16);
}

// ---------------- one prep kernel: all weight splits + Af table ----------------
__global__ void prep(const float* __restrict__ in_w, const float* __restrict__ xp_w,
                     const float* __restrict__ out_w, const float* __restrict__ A_log,
                     unsigned short* __restrict__ iwh, unsigned short* __restrict__ iwl,
                     unsigned short* __restrict__ xpwh, unsigned short* __restrict__ xpwl,
                     unsigned short* __restrict__ owh, unsigned short* __restrict__ owl,
                     float* __restrict__ Af) {
    const int i = blockIdx.x * 256 + threadIdx.x;
    if (i < N_INW) { unsigned short h, l; splitf(in_w[i], h, l); iwh[i] = h; iwl[i] = l; }
    if (i < N_XPW) {
        int ly = i / (NXPP * DI), rem = i % (NXPP * DI);
        int c = rem / DI, k = rem % DI;
        unsigned short h = 0, l = 0;
        if (c < NXP) splitf(xp_w[((size_t)ly * NXP + c) * DI + k], h, l);
        xpwh[i] = h; xpwl[i] = l;
    }
    if (i < N_OW) { unsigned short h, l; splitf(out_w[i], h, l); owh[i] = h; owl[i] = l; }
    if (i < N_AF) Af[i] = -expf(A_log[i]) * LOG2E;
}

// ---------------- transpose (B,C,L) -> (B,L,C), emit split bf16 ----------------
__global__ void transpose_in(const float* __restrict__ x, unsigned short* __restrict__ hh,
                             unsigned short* __restrict__ hl) {
    __shared__ float tl[32][33];
    const int b  = blockIdx.x;
    const int c0 = blockIdx.y * 32;
    const int l0 = blockIdx.z * 32;
    const int tx = threadIdx.x;
    const int ty = threadIdx.y;
    #pragma unroll
    for (int r = 0; r < 4; ++r) {
        int c = c0 + ty + r * 8;
        tl[ty + r * 8][tx] = x[((size_t)b * DIMC + c) * L_SEQ + l0 + tx];
    }
    __syncthreads();
    #pragma unroll
    for (int r = 0; r < 4; ++r) {
        int l = l0 + ty + r * 8;
        float v = tl[tx][ty + r * 8];
        size_t o = ((size_t)b * L_SEQ + l) * DIMC + c0 + tx;
        unsigned short h16, l16; splitf(v, h16, l16);
        hh[o] = h16; hl[o] = l16;
    }
}

// ---------------- MFMA GEMM: C[M,N] = A[M,K] * W[N,K]^T  (split-bf16, 3-pass) ----------------
template<int BM, int BN>
__global__ __launch_bounds__(256) void gemm_sp(
    const unsigned short* __restrict__ Ahg, const unsigned short* __restrict__ Alg,
    const unsigned short* __restrict__ Whg, const unsigned short* __restrict__ Wlg,
    float* __restrict__ C, int M, int N, int K) {
    constexpr int PS = 40;
    __shared__ unsigned short lds[(BM + BN) * 2 * PS];
    unsigned short* LAh = lds;
    unsigned short* LAl = LAh + BM * PS;
    unsigned short* LBh = LAl + BM * PS;
    unsigned short* LBl = LBh + BN * PS;
    const int t = threadIdx.x;
    const int w = t >> 6, l = t & 63;
    const int wr = w >> 1, wc = w & 1;
    const int lr = l & 15, lq = l >> 4;
    constexpr int MF = BM / 32, NF = BN / 32;
    const int bm = blockIdx.x * BM, bn = blockIdx.y * BN;
    f32x4 acc[MF][NF];
    const f32x4 z4 = {0.f, 0.f, 0.f, 0.f};
    #pragma unroll
    for (int m = 0; m < MF; ++m)
        #pragma unroll
        for (int n = 0; n < NF; ++n) acc[m][n] = z4;

    for (int k0 = 0; k0 < K; k0 += 32) {
        if (k0) __syncthreads();
        #pragma unroll
        for (int s = 0; s < BM * 4 / 256; ++s) {
            int task = t + s * 256;
            int r = task >> 2, g = task & 3;
            size_t go = (size_t)(bm + r) * K + k0 + g * 8;
            *(u16x8*)&LAh[r * PS + g * 8] = *(const u16x8*)&Ahg[go];
            *(u16x8*)&LAl[r * PS + g * 8] = *(const u16x8*)&Alg[go];
        }
        #pragma unroll
        for (int s = 0; s < BN * 4 / 256; ++s) {
            int task = t + s * 256;
            int r = task >> 2, g = task & 3;
            size_t go = (size_t)(bn + r) * K + k0 + g * 8;
            *(u16x8*)&LBh[r * PS + g * 8] = *(const u16x8*)&Whg[go];
            *(u16x8*)&LBl[r * PS + g * 8] = *(const u16x8*)&Wlg[go];
        }
        __syncthreads();
        u16x8 ah[MF], al[MF], bh[NF], bl[NF];
        #pragma unroll
        for (int m = 0; m < MF; ++m) {
            int rr = wr * (BM / 2) + m * 16 + lr;
            ah[m] = *(u16x8*)&LAh[rr * PS + lq * 8];
            al[m] = *(u16x8*)&LAl[rr * PS + lq * 8];
        }
        #pragma unroll
        for (int n = 0; n < NF; ++n) {
            int rr = wc * (BN / 2) + n * 16 + lr;
            bh[n] = *(u16x8*)&LBh[rr * PS + lq * 8];
            bl[n] = *(u16x8*)&LBl[rr * PS + lq * 8];
        }
        #pragma unroll
        for (int m = 0; m < MF; ++m)
            #pragma unroll
            for (int n = 0; n < NF; ++n) {
                asm("v_mfma_f32_16x16x32_bf16 %0, %1, %2, %0" : "+v"(acc[m][n]) : "v"(ah[m]), "v"(bh[n]));
                asm("v_mfma_f32_16x16x32_bf16 %0, %1, %2, %0" : "+v"(acc[m][n]) : "v"(ah[m]), "v"(bl[n]));
                asm("v_mfma_f32_16x16x32_bf16 %0, %1, %2, %0" : "+v"(acc[m][n]) : "v"(al[m]), "v"(bh[n]));
            }
    }
    #pragma unroll
    for (int m = 0; m < MF; ++m)
        #pragma unroll
        for (int n = 0; n < NF; ++n) {
            int col = bn + wc * (BN / 2) + n * 16 + lr;
            #pragma unroll
            for (int r = 0; r < 4; ++r) {
                int row = bm + wr * (BM / 2) + m * 16 + lq * 4 + r;
                C[(size_t)row * N + col] = acc[m][n][r];
            }
        }
}

// ======== fused: conv+silu -> x_proj MFMA -> dt+softplus -> scanA ========
__global__ __launch_bounds__(256) void fused_mid(
    const float* __restrict__ xz,
    const unsigned short* __restrict__ xpwh, const unsigned short* __restrict__ xpwl,
    const float* __restrict__ dtw, const float* __restrict__ dtb,
    const float* __restrict__ cw, const float* __restrict__ cb,
    const float* __restrict__ Af_g,
    float* __restrict__ xdbl, float* __restrict__ paO, float* __restrict__ hO) {
    const int ch = blockIdx.x & (NCH - 1);
    const int d  = threadIdx.x;
    const size_t r0 = (size_t)(blockIdx.x >> 8) * L_SEQ + ch * CS;
    __shared__ unsigned short aS[2][CS][PSA];    // split xc tile (16896 B), preserved
    __shared__ float P[4][CS][49];               // MFMA partials (12544 B)
    __shared__ float xdblS[CS][41];              // 2624 B

    // ---- phase 0: conv + silu on the fly, split into LDS ----
    {
        const float w0 = cw[d * 4 + 0], w1 = cw[d * 4 + 1];
        const float w2 = cw[d * 4 + 2], w3 = cw[d * 4 + 3];
        const float bz = cb[d];
        float p0 = 0.f, p1 = 0.f, p2 = 0.f;
        if (ch > 0) {
            p0 = xz[(r0 - 3) * 512 + d];
            p1 = xz[(r0 - 2) * 512 + d];
            p2 = xz[(r0 - 1) * 512 + d];
        }
        #pragma unroll 4
        for (int i = 0; i < CS; ++i) {
            float cur = xz[(r0 + i) * 512 + d];
            float v = silu_f(fmaf(w3, cur, fmaf(w2, p2, fmaf(w1, p1, fmaf(w0, p0, bz)))));
            unsigned short h16, l16; splitf(v, h16, l16);
            aS[0][i][d] = h16; aS[1][i][d] = l16;
            p0 = p1; p1 = p2; p2 = cur;
        }
    }
    __syncthreads();

    // ---- phase 1: x_proj MFMA (M=16, N=48), waves split K (each 64) ----
    const int w = threadIdx.x >> 6, l = threadIdx.x & 63;
    const int lr = l & 15, lq = l >> 4;
    {
        f32x4 acc[3];
        const f32x4 z4 = {0.f, 0.f, 0.f, 0.f};
        #pragma unroll
        for (int n = 0; n < 3; ++n) acc[n] = z4;
        #pragma unroll
        for (int ks = 0; ks < 2; ++ks) {
            const int kk = w * 64 + ks * 32 + lq * 8;
            u16x8 ah, al, bh[3], bl[3];
            ah = *(const u16x8*)&aS[0][lr][kk];
            al = *(const u16x8*)&aS[1][lr][kk];
            #pragma unroll
            for (int n = 0; n < 3; ++n) {
                const int c = n * 16 + lr;
                bh[n] = *(const u16x8*)&xpwh[c * DI + kk];
                bl[n] = *(const u16x8*)&xpwl[c * DI + kk];
            }
            #pragma unroll
            for (int n = 0; n < 3; ++n) {
                asm("v_mfma_f32_16x16x32_bf16 %0, %1, %2, %0" : "+v"(acc[n]) : "v"(ah), "v"(bh[n]));
                asm("v_mfma_f32_16x16x32_bf16 %0, %1, %2, %0" : "+v"(acc[n]) : "v"(ah), "v"(bl[n]));
                asm("v_mfma_f32_16x16x32_bf16 %0, %1, %2, %0" : "+v"(acc[n]) : "v"(al), "v"(bh[n]));
            }
        }
        #pragma unroll
        for (int n = 0; n < 3; ++n)
            #pragma unroll
            for (int r = 0; r < 4; ++r)
                P[w][lq * 4 + r][n * 16 + lr] = acc[n][r];
    }
    __syncthreads();
    // ---- phase 2: reduce 4 partials -> xdblS + global xdbl ----
    {
        const int i = threadIdx.x >> 4;        // 0..15
        const int cb0 = threadIdx.x & 15;
        for (int c = cb0; c < NXP; c += 16) {
            float s = P[0][i][c] + P[1][i][c] + P[2][i][c] + P[3][i][c];
            xdblS[i][c] = s;
            xdbl[(r0 + i) * NXP + c] = s;
        }
    }
    __syncthreads();

    // ---- phase 3: dt + softplus + scanA (zero init), u rebuilt from aS ----
    float wt[DTR];
    #pragma unroll
    for (int r = 0; r < DTR; ++r) wt[r] = dtw[d * DTR + r];
    const float bt = dtb[d];
    float Af[DST], h[DST], pa[DST];
    #pragma unroll
    for (int n = 0; n < DST; ++n) {
        Af[n] = Af_g[d * DST + n];
        h[n] = 0.f; pa[n] = 1.f;
    }
    #pragma unroll 4
    for (int i = 0; i < CS; ++i) {
        float s = bt;
        #pragma unroll
        for (int r = 0; r < DTR; ++r) s = fmaf(xdblS[i][r], wt[r], s);
        const float dl = softplus_f(s);
        const float u = bf2f(aS[0][i][d]) + bf2f(aS[1][i][d]);
        const float du = dl * u;
        #pragma unroll
        for (int n = 0; n < DST; ++n) {
            const float dA = fexp2(dl * Af[n]);
            pa[n] *= dA;
            h[n] = fmaf(dA, h[n], du * xdblS[i][DTR + n]);
        }
    }
    const size_t o = ((size_t)blockIdx.x * DI + d) * DST;
    #pragma unroll
    for (int n = 0; n < DST; ++n) { paO[o + n] = pa[n]; hO[o + n] = h[n]; }
}

// ---------------- combine chunk states; paO becomes exclusive init ----------------
// 64-thread blocks x 128 blocks: 4x more CUs active than 256x32 (memory-parallelism).
__global__ void scan_combine(float* __restrict__ paO, const float* __restrict__ hO) {
    const int t  = blockIdx.x * 64 + threadIdx.x;   // over B*DI*DST = 8192
    const int b  = t / (DI * DST);
    const int dn = t % (DI * DST);
    float run = 0.f;
    for (int ch0 = 0; ch0 < NCH; ch0 += 8) {
        float pav[8], hv[8];
        #pragma unroll
        for (int j = 0; j < 8; ++j) {
            size_t o = ((size_t)(b * NCH + ch0 + j)) * DI * DST + dn;
            pav[j] = paO[o]; hv[j] = hO[o];
        }
        #pragma unroll
        for (int j = 0; j < 8; ++j) {
            size_t o = ((size_t)(b * NCH + ch0 + j)) * DI * DST + dn;
            paO[o] = run;
            run = fmaf(pav[j], run, hv[j]);
        }
    }
}

// ======== fused: conv on-the-fly -> scanC + gate -> out_proj (MFMA) ========
__global__ __launch_bounds__(256) void fused_out(
    const float* __restrict__ xz, const float* __restrict__ xdbl,
    const unsigned short* __restrict__ owh, const unsigned short* __restrict__ owl,
    const float* __restrict__ dtw, const float* __restrict__ dtb,
    const float* __restrict__ cw, const float* __restrict__ cb,
    const float* __restrict__ Af_g, const float* __restrict__ D_skip,
    const float* __restrict__ hinit,
    unsigned short* __restrict__ hh, unsigned short* __restrict__ hl) {
    const int ch = blockIdx.x & (NCH - 1);
    const int d  = threadIdx.x;
    const size_t r0 = (size_t)(blockIdx.x >> 8) * L_SEQ + ch * CS;
    __shared__ unsigned short yS[2][CS][PSA];    // 16896 B
    __shared__ float xdblS[CS][41];              // 2624 B

    {
        const float* src = xdbl + r0 * NXP;
        for (int idx = threadIdx.x; idx < CS * NXP; idx += 256)
            xdblS[idx / NXP][idx % NXP] = src[idx];
    }
    float wt[DTR];
    #pragma unroll
    for (int r = 0; r < DTR; ++r) wt[r] = dtw[d * DTR + r];
    const float bt = dtb[d];
    const float Dd = D_skip[d];
    const float w0 = cw[d * 4 + 0], w1 = cw[d * 4 + 1];
    const float w2 = cw[d * 4 + 2], w3 = cw[d * 4 + 3];
    const float bz = cb[d];
    float Af[DST], h[DST];
    const size_t o = ((size_t)blockIdx.x * DI + d) * DST;
    #pragma unroll
    for (int n = 0; n < DST; ++n) {
        Af[n] = Af_g[d * DST + n];
        h[n] = hinit[o + n];
    }
    float p0 = 0.f, p1 = 0.f, p2 = 0.f;
    if (ch > 0) {
        p0 = xz[(r0 - 3) * 512 + d];
        p1 = xz[(r0 - 2) * 512 + d];
        p2 = xz[(r0 - 1) * 512 + d];
    }
    __syncthreads();

    // ---- scanC + skip + gate (conv inline), y split into LDS ----
    #pragma unroll 4
    for (int i = 0; i < CS; ++i) {
        const float cur = xz[(r0 + i) * 512 + d];
        const float zv  = xz[(r0 + i) * 512 + DI + d];
        const float u = silu_f(fmaf(w3, cur, fmaf(w2, p2, fmaf(w1, p1, fmaf(w0, p0, bz)))));
        p0 = p1; p1 = p2; p2 = cur;
        float s = bt;
        #pragma unroll
        for (int r = 0; r < DTR; ++r) s = fmaf(xdblS[i][r], wt[r], s);
        const float dl = softplus_f(s);
        const float du = dl * u;
        float acc = 0.f;
        #pragma unroll
        for (int n = 0; n < DST; ++n) {
            const float dA = fexp2(dl * Af[n]);
            h[n] = fmaf(dA, h[n], du * xdblS[i][DTR + n]);
            acc = fmaf(h[n], xdblS[i][DTR + DST + n], acc);
        }
        const float y = (acc + u * Dd) * silu_f(zv);
        unsigned short h16, l16; splitf(y, h16, l16);
        yS[0][i][d] = h16; yS[1][i][d] = l16;
    }
    __syncthreads();

    // ---- out_proj MFMA: M=16 rows, wave w owns cols w*32..w*32+31, K=256 ----
    const int w = threadIdx.x >> 6, l = threadIdx.x & 63;
    const int lr = l & 15, lq = l >> 4;
    f32x4 acc[2];
    const f32x4 z4 = {0.f, 0.f, 0.f, 0.f};
    #pragma unroll
    for (int n = 0; n < 2; ++n) acc[n] = z4;
    #pragma unroll
    for (int ks = 0; ks < 8; ++ks) {
        const int kk = ks * 32 + lq * 8;
        u16x8 ah, al, bh[2], bl[2];
        ah = *(const u16x8*)&yS[0][lr][kk];
        al = *(const u16x8*)&yS[1][lr][kk];
        #pragma unroll
        for (int n = 0; n < 2; ++n) {
            const int c = w * 32 + n * 16 + lr;
            bh[n] = *(const u16x8*)&owh[c * DI + kk];
            bl[n] = *(const u16x8*)&owl[c * DI + kk];
        }
        #pragma unroll
        for (int n = 0; n < 2; ++n) {
            asm("v_mfma_f32_16x16x32_bf16 %0, %1, %2, %0" : "+v"(acc[n]) : "v"(ah), "v"(bh[n]));
            asm("v_mfma_f32_16x16x32_bf16 %0, %1, %2, %0" : "+v"(acc[n]) : "v"(ah), "v"(bl[n]));
            asm("v_mfma_f32_16x16x32_bf16 %0, %1, %2, %0" : "+v"(acc[n]) : "v"(al), "v"(bh[n]));
        }
    }
    #pragma unroll
    for (int n = 0; n < 2; ++n) {
        const int col = w * 32 + n * 16 + lr;
        #pragma unroll
        for (int r = 0; r < 4; ++r) {
            const size_t row = r0 + lq * 4 + r;
            unsigned short h16, l16; splitf(acc[n][r], h16, l16);
            hh[row * DIMC + col] = h16;
            hl[row * DIMC + col] = l16;
        }
    }
}

// ---------------- RMSNorm over C=128 + transpose (B,L,C) -> (B,C,L) ----------------
__global__ void rms_out(const unsigned short* __restrict__ hh, const unsigned short* __restrict__ hl,
                        const float* __restrict__ rw, float* __restrict__ out) {
    __shared__ float tile[64][129];
    __shared__ float rinv[64];
    const int blk = blockIdx.x;
    const int b = blk / (L_SEQ / 64);
    const int l0 = (blk % (L_SEQ / 64)) * 64;
    const int t = threadIdx.x;
    for (int k = 0; k < 32; ++k) {
        int idx = k * 256 + t;
        int l = idx >> 7, cc = idx & 127;
        size_t o = ((size_t)b * L_SEQ + l0 + l) * DIMC + cc;
        tile[l][cc] = bf2f(hh[o]) + bf2f(hl[o]);
    }
    __syncthreads();
    if (t < 64) {
        float s = 0.f;
        for (int cc = 0; cc < DIMC; ++cc) { float v = tile[t][cc]; s += v * v; }
        rinv[t] = rsqrtf(s / DIMC + 1e-6f);
    }
    __syncthreads();
    for (int k = 0; k < 32; ++k) {
        int odx = k * 256 + t;
        int cc = odx >> 6, li = odx & 63;
        out[((size_t)b * DIMC + cc) * L_SEQ + l0 + li] = tile[li][cc] * rinv[li] * rw[cc];
    }
}

extern "C" void kernel_launch(void* const* d_in, const int* in_sizes, int n_in,
                              void* d_out, int out_size, void* d_ws, size_t ws_size,
                              hipStream_t stream) {
    const float* x      = (const float*)d_in[0];
    const float* in_w   = (const float*)d_in[1];
    const float* conv_w = (const float*)d_in[2];
    const float* conv_b = (const float*)d_in[3];
    const float* xp_w   = (const float*)d_in[4];
    const float* dt_w   = (const float*)d_in[5];
    const float* dt_b   = (const float*)d_in[6];
    const float* A_log  = (const float*)d_in[7];
    const float* D_skip = (const float*)d_in[8];
    const float* out_w  = (const float*)d_in[9];
    const float* rms_w  = (const float*)d_in[10];
    float* out = (float*)d_out;

    const int M = B_SZ * L_SEQ;   // 8192
    char* p = (char*)d_ws;
    auto alloc = [&](size_t bytes) -> void* {
        void* r = (void*)p; p += (bytes + 255) & ~(size_t)255; return r;
    };
    float* xz   = (float*)alloc((size_t)M * 512 * 4);
    float* xdbl = (float*)alloc((size_t)M * NXP * 4);
    float* paB  = (float*)alloc((size_t)B_SZ * NCH * DI * DST * 4);
    float* hB   = (float*)alloc((size_t)B_SZ * NCH * DI * DST * 4);
    float* AfT  = (float*)alloc((size_t)N_AF * 4);
    unsigned short* hh0 = (unsigned short*)alloc((size_t)M * DIMC * 2);
    unsigned short* hl0 = (unsigned short*)alloc((size_t)M * DIMC * 2);
    unsigned short* hh1 = (unsigned short*)alloc((size_t)M * DIMC * 2);
    unsigned short* hl1 = (unsigned short*)alloc((size_t)M * DIMC * 2);
    unsigned short* iwh = (unsigned short*)alloc((size_t)N_INW * 2);
    unsigned short* iwl = (unsigned short*)alloc((size_t)N_INW * 2);
    unsigned short* xpwh = (unsigned short*)alloc((size_t)N_XPW * 2);
    unsigned short* xpwl = (unsigned short*)alloc((size_t)N_XPW * 2);
    unsigned short* owh = (unsigned short*)alloc((size_t)N_OW * 2);
    unsigned short* owl = (unsigned short*)alloc((size_t)N_OW * 2);

    prep<<<(N_INW + 255) / 256, 256, 0, stream>>>(
        in_w, xp_w, out_w, A_log, iwh, iwl, xpwh, xpwl, owh, owl, AfT);

    transpose_in<<<dim3(B_SZ, DIMC / 32, L_SEQ / 32), dim3(32, 8), 0, stream>>>(x, hh0, hl0);

    unsigned short *hhin = hh0, *hlin = hl0, *hhout = hh1, *hlout = hl1;
    for (int layer = 0; layer < NLAYER; ++layer) {
        const float* cw  = conv_w + (size_t)layer * DI * 4;
        const float* cb  = conv_b + (size_t)layer * DI;
        const float* dtw = dt_w   + (size_t)layer * DI * DTR;
        const float* dtb = dt_b   + (size_t)layer * DI;
        const float* af  = AfT    + (size_t)layer * DI * DST;
        const float* ds  = D_skip + (size_t)layer * DI;
        const size_t iwo = (size_t)layer * 512 * 128;
        const size_t xpo = (size_t)layer * NXPP * DI;
        const size_t owo = (size_t)layer * DIMC * DI;

        // in_proj: xz = h * in_w^T   (M x 512, K=128), 64x128 tile -> 512 blocks
        gemm_sp<64, 128><<<dim3(M / 64, 4), 256, 0, stream>>>(
            hhin, hlin, iwh + iwo, iwl + iwo, xz, M, 512, 128);
        // conv+silu -> x_proj (MFMA) -> dt -> scanA
        fused_mid<<<B_SZ * NCH, 256, 0, stream>>>(
            xz, xpwh + xpo, xpwl + xpo, dtw, dtb, cw, cb, af, xdbl, paB, hB);
        scan_combine<<<(B_SZ * DI * DST) / 64, 64, 0, stream>>>(paB, hB);
        // scanC + gate -> out_proj (MFMA) -> split
        fused_out<<<B_SZ * NCH, 256, 0, stream>>>(
            xz, xdbl, owh + owo, owl + owo, dtw, dtb, cw, cb, af, ds, paB,
            hhout, hlout);

        unsigned short* ts;
        ts = hhin; hhin = hhout; hhout = ts;
        ts = hlin; hlin = hlout; hlout = ts;
    }

    rms_out<<<B_SZ * (L_SEQ / 64), 256, 0, stream>>>(hhin, hlin, rms_w, out);
}